// Round 7
// baseline (117.432 us; speedup 1.0000x reference)
//
#include <hip/hip_runtime.h>

// COO SpMM: out[r,:] = sum_e vals[e] * seq[cols[e],:], rows sorted.
// N=50000, E=1.25M, D=64, fp32 in/out.
//
// R1: 256B gathers, atomic flush             -> 56.6 us
// R2: deep double-buffer                     -> 66.5 us FAIL
// R3: interleaved streams + dword atomics    -> 270 us FAIL
// R4: float4 + ownership, scalar meta        -> 60 us
// R5: coalesced meta, 16x1KB gathers, RPS=2  -> 53 us
// R6: RPS=1, oversubscribed, depth 8, fp32   -> ~41 us spmm
// R7: bf16 gather table (6.4 MB)             -> harness 98.6 us
//     (fill ~45 fixed + prep ~8 + spmm ~41; bytes-halving bought 0)
// R8: concurrent feature-split halves        -> 111 FAIL (XCD parity myth)
// R9: temporal column partition (2 phases)   -> 126 FAIL (scan dominates)
// R10: halved vmem instrs + meta prefetch    -> 103 FAIL (no spmm gain)
// R11: fp32-direct BUT 32-lane subs          -> 113.6 FAIL: geometry broke
//      the gather engine (0.5 instr/edge, 2 rows/instr, spmm ~66).
//
// MODEL: spmm is bound by random line-transaction rate ~30 G txn/s
//   (1.25M txns / 41.7 us), independent of txn SIZE (128B bf16 == 256B
//   fp32) and of table residency — but reaching that wall REQUIRES the
//   R6/R7 issue geometry (16-lane subs, 0.25 vmem instr/edge, depth>=8
//   independent gathers, ~60 VGPR -> 8 waves/SIMD). 1 txn/edge is the
//   gather floor; bytes/residency are non-levers.
// R12: R6's exact spmm geometry (fp32 direct, float4, depth 8)
//   + table-free prep (row_ptr only, ~1.5 us instead of ~8).
//   Predicted total ~89-92 us; exact-fp32 gather arithmetic.
//   (R12 first submit: container infra failure, never ran. Resubmit.)

#define WPB 4               // waves per 256-thread block

// row_start[t] = first edge e with rows[e] >= t, t in [0, n_nodes].
__global__ __launch_bounds__(256) void row_ptr_kernel(
    const int* __restrict__ rows, int* __restrict__ row_start,
    int n_edges, int n_nodes)
{
    const int e = blockIdx.x * blockDim.x + threadIdx.x;
    if (e >= n_edges) return;
    const int r    = rows[e];
    const int prev = (e == 0) ? -1 : rows[e - 1];
    for (int t = prev + 1; t <= r; ++t) row_start[t] = e;
    if (e == n_edges - 1)
        for (int t = r + 1; t <= n_nodes; ++t) row_start[t] = n_edges;
}

__global__ __launch_bounds__(256) void spmm_kernel(
    const float4* __restrict__ seq,       // [N][16] float4 = [N][64] fp32
    const float* __restrict__ vals,       // [E]
    const int*   __restrict__ cols,       // [E]
    const int*   __restrict__ row_start,  // [N+1]
    float*       __restrict__ out,        // [N, 64] fp32
    int n_nodes, int n_edges)
{
    const int lane = threadIdx.x & 63;
    const int sub  = lane >> 4;           // 16-lane sub-wave id (0..3)
    const int fl   = lane & 15;           // float4 slot: feats 4*fl..4*fl+3
    const int ml   = fl & 7;              // meta slot within chunk of 8
    const int wave = blockIdx.x * WPB + (threadIdx.x >> 6);

    const int r = wave * 4 + sub;         // one row per 16-lane sub
    if (wave * 4 >= n_nodes) return;      // wave-uniform exit
    const bool valid = (r < n_nodes);

    int e = 0, e_end = 0;
    if (valid) {
        e     = row_start[r];
        e_end = row_start[r + 1];
    }

    float4 acc = make_float4(0.f, 0.f, 0.f, 0.f);

    while (__any(e < e_end)) {
        // coalesced metadata: next 8 edges of this sub
        // (lanes 8..15 load duplicates; only lanes 0..7 used as sources)
        int cidx = e + ml;
        if (cidx >= n_edges) cidx = n_edges - 1;
        const int   c = cols[cidx];
        const float v = vals[cidx];

        // 8 independent gathers; each instr = 64 lanes x 16 B = 4 rows
        // of 256 B (0.25 vmem instr/edge). Whole chunk in one latency
        // round; a sub's 16 lanes read one full fp32 row (1 txn/edge).
        float4 x[8];
#pragma unroll
        for (int u = 0; u < 8; ++u) {
            const int cu = __shfl(c, (sub << 4) | u);   // sub-local bcast
            if (e + u < e_end)
                x[u] = seq[(cu << 4) + fl];             // 16 B: 4 fp32 feats
        }
#pragma unroll
        for (int u = 0; u < 8; ++u) {
            const float vu = __shfl(v, (sub << 4) | u);
            if (e + u < e_end) {
                acc.x = fmaf(vu, x[u].x, acc.x);
                acc.y = fmaf(vu, x[u].y, acc.y);
                acc.z = fmaf(vu, x[u].z, acc.z);
                acc.w = fmaf(vu, x[u].w, acc.w);
            }
        }
        e += 8;
    }

    // one 16 B store per lane; a sub's 16 lanes = contiguous 256 B row.
    // Also zeroes empty rows.
    if (valid)
        ((float4*)out)[(r << 4) + fl] = acc;
}

extern "C" void kernel_launch(void* const* d_in, const int* in_sizes, int n_in,
                              void* d_out, int out_size, void* d_ws, size_t ws_size,
                              hipStream_t stream) {
    const float* seq  = (const float*)d_in[0];
    const float* vals = (const float*)d_in[1];
    const int*   rows = (const int*)d_in[2];
    const int*   cols = (const int*)d_in[3];
    float*       out  = (float*)d_out;

    const int n_edges = in_sizes[1];            // E
    const int n_nodes = out_size / 64;          // N (out is [1,N,64])

    // ws layout: [row_start: (N+1) ints] — no table build
    int* row_start = (int*)d_ws;

    {
        const int threads = 256;
        const int blocks  = (n_edges + threads - 1) / threads;
        row_ptr_kernel<<<blocks, threads, 0, stream>>>(rows, row_start,
                                                       n_edges, n_nodes);
    }
    {
        const int waves  = (n_nodes + 3) / 4;   // one row per 16-lane sub
        const int blocks = (waves + WPB - 1) / WPB;
        spmm_kernel<<<blocks, 256, 0, stream>>>(
            (const float4*)seq, vals, cols, row_start, out,
            n_nodes, n_edges);
    }
}